// Round 7
// baseline (169885.254 us; speedup 1.0000x reference)
//
#include <hip/hip_runtime.h>
#include <cstdint>
#include <cstddef>
#include <math.h>

// Exact Viterbi decode: N=512 states, T=8192, M=50257 tokens.
// R7: (a) group-of-4 double-buffered scan pipeline (batch SV-index reads +
//     32 global loads per group; merge prev group under next group's
//     latency). R6 instrumentation showed 1-deep prefetch serialized at
//     ~1.4k cy/row because next row's loads depend on an LDS index read.
// (b) extras machinery OFF the common path: lag-1 deferred check sets a
//     poison flag; viterbi_fallback (full unpruned exact forward) reruns
//     everything iff poisoned. Margin analysis (0.107 < DELTA_W=0.15) says
//     never; exactness is unconditional via the fallback. 4 -> 2 barriers.
// (c) diagnostics kept: WRITE_SIZE extra pages P = mean_n + 512*min(7,cyc/4096).
// Merge rule everywhere: (value strict >, tie -> smaller row index) =>
// exact first-index argmax, order-independent; dup-pad merges idempotent.

#define NT 512
#define TT 8192
#define MT 50257
#define DELTA_W 0.15f
#define NEG_INF (-3.402823466e38f)

#define BT_L 32                  // backtrace segment length
#define BT_S (TT / BT_L)         // 256 segments

// ---- workspace layout (bytes) ----
#define WS_LOGPI   0u            // 512 f32
#define WS_VLAST   2048u         // 512 f32
#define WS_BOUND   4096u         // 257 i32
#define WS_FLAG    5248u         // 1 i32 poison flag (zeroed by prep_logs)
#define WS_ROWMAX  5632u         // 512 f32
#define WS_MAPS    8192u         // 256*512 u16 = 262144
#define WS_LA      270336u       // 512*512 f32 = 1048576 (row-major logA)
#define WS_EMIS    1318912u      // 8192*512 f32 = 16777216 (diag scratch after fwd, only if clean)
#define WS_BP      18096128u     // 8192*512 u16 = 8388608
#define WS_NEED    26484736u

// Correctly-rounded fp32 logs via fp64 (verified: absmax 0 vs numpy ref).
__global__ void prep_logs(const float* __restrict__ A, const float* __restrict__ Pi,
                          float* __restrict__ lA, float* __restrict__ logPi,
                          int* __restrict__ poison) {
    int idx = blockIdx.x * blockDim.x + threadIdx.x;
    if (idx < NT * NT) {
        lA[idx] = (float)log((double)A[idx]);
    } else if (idx < NT * NT + NT) {
        int j = idx - NT * NT;
        logPi[j] = (float)log((double)Pi[j]);
    } else if (idx == NT * NT + NT) {
        *poison = 0;
    }
}

__global__ void prep_rowmax(const float* __restrict__ lA, float* __restrict__ rowmax) {
    __shared__ float s[4];
    int i = blockIdx.x;
    int t = threadIdx.x;                    // 256 threads
    float m = fmaxf(lA[i * NT + t], lA[i * NT + t + 256]);
    for (int k = 32; k >= 1; k >>= 1) m = fmaxf(m, __shfl_xor(m, k, 64));
    if ((t & 63) == 0) s[t >> 6] = m;
    __syncthreads();
    if (t == 0) {
        float r = fmaxf(fmaxf(s[0], s[1]), fmaxf(s[2], s[3]));
        rowmax[i] = r;
    }
}

__global__ void prep_emis(const float* __restrict__ B, const int* __restrict__ tok,
                          float* __restrict__ emis) {
    int idx = blockIdx.x * blockDim.x + threadIdx.x;   // t*512 + j
    if (idx >= TT * NT) return;
    int t = idx >> 9;
    int j = idx & (NT - 1);
    int tk = tok[t];
    float e;
    if (tk < 0) e = (float)log((double)(1.0f / 512.0f));
    else        e = (float)log((double)B[(size_t)j * MT + tk]);
    emis[idx] = e;
}

// 512 threads / 8 waves. 2 barriers per step.
__launch_bounds__(NT, 1)
__global__ void viterbi_fwd_exact(const float* __restrict__ lA,
                                  const float* __restrict__ rowmax,
                                  const float* emis,          // aliases diag scratch
                                  const float* __restrict__ logPi,
                                  unsigned short* __restrict__ bp,
                                  float* __restrict__ vlast,
                                  int* __restrict__ poison,
                                  float* scratch) {
    __shared__ float2 SV[2][560];            // double-buffered survivors (v, idx bits)
    __shared__ alignas(16) float redR[8];    // rowmax partials
    __shared__ alignas(16) float redT[8];    // per-wave tmin (lag-1 checked)
    __shared__ int nCtr[2];
    __shared__ int sPoison;
    __shared__ int Pshare;
    __shared__ float2 part[8][NT];           // per-wave column partials (32 KiB)

    const int tid  = threadIdx.x;
    const int j    = tid;                    // column owned
    const int lane = tid & 63;
    const int wave = tid >> 6;               // 0..7
    const unsigned long long below = (1ull << lane) - 1ull;

    // ---- preamble: warm lA into L2; R; counters; v0 ----
    float acc = 0.0f;
    {
        const float4* lAf4 = (const float4*)lA;
        for (int k = tid; k < (NT * NT) / 4; k += NT) acc += lAf4[k].x;
    }
    float r = rowmax[j];
    #pragma unroll
    for (int d = 1; d <= 32; d <<= 1) r = fmaxf(r, __shfl_xor(r, d, 64));
    if (lane == 0) redR[wave] = r;
    if (tid == 0) { nCtr[0] = 0; nCtr[1] = 0; sPoison = 0; }
    __syncthreads();
    float4 rr0 = *(const float4*)redR;
    float4 rr1 = *(const float4*)(redR + 4);
    const float R = fmaxf(fmaxf(fmaxf(rr0.x, rr0.y), fmaxf(rr0.z, rr0.w)),
                          fmaxf(fmaxf(rr1.x, rr1.y), fmaxf(rr1.z, rr1.w)));
    if (acc == 1.2345e30f && j == 511) redR[0] = acc;    // keep warm loads alive

    float v = logPi[j] + emis[j];            // exact v0 (single-rounded == ref)
    float vChk = 0.0f;                       // step t-1's incoming v
    bool  predChk = true;                    // step t-1's selection
    long long c0 = 0, nAcc = 0;
    if (tid == 0) c0 = clock64();

    for (int t = 1; t < TT; ++t) {
        const int p = t & 1;
        // ---- PH1: emis issue (nt); per-wave select; compact ----
        float e = __builtin_nontemporal_load(emis + (size_t)t * NT + j);
        float wm = v;
        #pragma unroll
        for (int d = 1; d <= 32; d <<= 1) wm = fmaxf(wm, __shfl_xor(wm, d, 64));
        bool pred = (v >= wm - DELTA_W);     // per-wave max always selected
        unsigned long long mk = __ballot(pred);
        int base = 0;
        if (lane == 0) base = atomicAdd(&nCtr[p], __popcll(mk));
        base = __shfl(base, 0, 64);
        if (pred) SV[p][base + __popcll(mk & below)] = make_float2(v, __int_as_float(j));
        __syncthreads();                     // B1: survivors final; redT(t-1) visible

        const int n   = nCtr[p];             // >= 8
        const int nm1 = n - 1;
        if (tid == 0) { nCtr[p ^ 1] = 0; nAcc += n; }

        // ---- scan prologue: group A = slots wave+{0,8,16,24} ----
        const float* lAl = lA + lane;
        float ga[4][8], va[4]; int ia[4];
        float gb[4][8], vb[4]; int ib[4];
        #pragma unroll
        for (int q = 0; q < 4; ++q) {
            int s = wave + (q << 3); int gs = s < n ? s : nm1;   // dup-pad
            float2 sv = SV[p][gs]; va[q] = sv.x; ia[q] = __float_as_int(sv.y);
            const float* rp = lAl + ((size_t)(unsigned)ia[q] << 9);
            #pragma unroll
            for (int k = 0; k < 8; ++k) ga[q][k] = rp[k << 6];
        }

        // ---- deferred lag-1 extras check (overlaps group-A latency) ----
        if (t > 1) {
            float4 t0 = *(const float4*)redT;
            float4 t1 = *(const float4*)(redT + 4);
            float T = fminf(fminf(fminf(t0.x, t0.y), fminf(t0.z, t0.w)),
                            fminf(fminf(t1.x, t1.y), fminf(t1.z, t1.w)));
            bool px = (vChk + R >= T) && !predChk;   // fl(v+R) monotone bound
            if (__ballot(px) != 0ull) { if (lane == 0) sPoison = 1; }
        }

        // ---- pipelined scan: merge group under next group's load latency ----
        float mv[8]; int bi[8];
        #pragma unroll
        for (int k = 0; k < 8; ++k) { mv[k] = NEG_INF; bi[k] = 0x7fffffff; }
        int s0 = wave;
        while (true) {
            const int sB = s0 + 32;
            const bool moreB = (sB < n);
            if (moreB) {
                #pragma unroll
                for (int q = 0; q < 4; ++q) {
                    int s = sB + (q << 3); int gs = s < n ? s : nm1;
                    float2 sv = SV[p][gs]; vb[q] = sv.x; ib[q] = __float_as_int(sv.y);
                    const float* rp = lAl + ((size_t)(unsigned)ib[q] << 9);
                    #pragma unroll
                    for (int k = 0; k < 8; ++k) gb[q][k] = rp[k << 6];
                }
            }
            #pragma unroll
            for (int q = 0; q < 4; ++q)
                #pragma unroll
                for (int k = 0; k < 8; ++k) {
                    float sc = va[q] + ga[q][k];          // single-rounded add == ref
                    if (sc > mv[k] || (sc == mv[k] && ia[q] < bi[k])) {
                        mv[k] = sc; bi[k] = ia[q];
                    }
                }
            if (!moreB) break;
            const int sA = sB + 32;
            const bool moreA = (sA < n);
            if (moreA) {
                #pragma unroll
                for (int q = 0; q < 4; ++q) {
                    int s = sA + (q << 3); int gs = s < n ? s : nm1;
                    float2 sv = SV[p][gs]; va[q] = sv.x; ia[q] = __float_as_int(sv.y);
                    const float* rp = lAl + ((size_t)(unsigned)ia[q] << 9);
                    #pragma unroll
                    for (int k = 0; k < 8; ++k) ga[q][k] = rp[k << 6];
                }
            }
            #pragma unroll
            for (int q = 0; q < 4; ++q)
                #pragma unroll
                for (int k = 0; k < 8; ++k) {
                    float sc = vb[q] + gb[q][k];
                    if (sc > mv[k] || (sc == mv[k] && ib[q] < bi[k])) {
                        mv[k] = sc; bi[k] = ib[q];
                    }
                }
            if (!moreA) break;
            s0 = sA;
        }
        // write partials: col lane+64k (conflict-free per R6 counter)
        #pragma unroll
        for (int k = 0; k < 8; ++k)
            part[wave][lane + (k << 6)] = make_float2(mv[k], __int_as_float(bi[k]));
        __syncthreads();                     // B2: partials visible

        // ---- merge 8 partials for column j; tmin; finalize ----
        float mval = NEG_INF;
        int   bidx = 0x7fffffff;
        #pragma unroll
        for (int w = 0; w < 8; ++w) {
            const float2 q = part[w][j];
            const float val = q.x;
            const int   ii  = __float_as_int(q.y);
            if (val > mval || (val == mval && ii < bidx)) { mval = val; bidx = ii; }
        }
        float tmin = mval;
        #pragma unroll
        for (int d = 1; d <= 32; d <<= 1) tmin = fminf(tmin, __shfl_xor(tmin, d, 64));
        if (lane == 0) redT[wave] = tmin;    // read after B1 of step t+1

        float vn = mval + e;                 // single-rounded == ref
        __builtin_nontemporal_store((unsigned short)bidx, bp + (size_t)t * NT + j);
        if (t == TT - 1) vlast[j] = vn;
        vChk = v; predChk = pred;
        v = vn;
    }

    __syncthreads();                         // redT(TT-1) visible
    {   // final deferred check (step TT-1)
        float4 t0 = *(const float4*)redT;
        float4 t1 = *(const float4*)(redT + 4);
        float T = fminf(fminf(fminf(t0.x, t0.y), fminf(t0.z, t0.w)),
                        fminf(fminf(t1.x, t1.y), fminf(t1.z, t1.w)));
        bool px = (vChk + R >= T) && !predChk;
        if (__ballot(px) != 0ull) { if (lane == 0) sPoison = 1; }
    }
    __syncthreads();
    if (sPoison) {                           // ~never: hand off to exact fallback
        if (tid == 0) *poison = 1;           // leave emis intact for fallback
        return;
    }
    // ---- diagnostics (clean path only): P = mean_n + 512*min(7,cyc/4096) ----
    if (tid == 0) {
        long long cyc = (clock64() - c0) / (long long)(TT - 1);
        int b = (int)(cyc >> 12); if (b > 7) b = 7; if (b < 0) b = 0;
        int mn = (int)(nAcc / (long long)(TT - 1)); if (mn > 511) mn = 511;
        Pshare = mn + (b << 9);
    }
    __syncthreads();
    const int P = Pshare;                    // <= 4095 pages (fits emis region)
    for (int pg = 0; pg < P; ++pg) {
        unsigned long long val = ((unsigned long long)pg << 32) | (unsigned)tid;
        __builtin_nontemporal_store(val,
            (unsigned long long*)((char*)scratch + (size_t)pg * 4096) + tid);
    }
}

// Exact unpruned forward; runs only if poisoned (exactness safety net).
__launch_bounds__(NT, 1)
__global__ void viterbi_fallback(const float* __restrict__ lA,
                                 const float* __restrict__ emis,
                                 const float* __restrict__ logPi,
                                 const int* __restrict__ poison,
                                 unsigned short* __restrict__ bp,
                                 float* __restrict__ vlast) {
    if (*poison == 0) return;
    __shared__ float vcur[NT];
    __shared__ float2 part[8][NT];
    const int tid = threadIdx.x, j = tid, lane = tid & 63, wave = tid >> 6;
    vcur[j] = logPi[j] + emis[j];
    __syncthreads();
    for (int t = 1; t < TT; ++t) {
        float mv[8]; int bi[8];
        #pragma unroll
        for (int k = 0; k < 8; ++k) { mv[k] = NEG_INF; bi[k] = 0x7fffffff; }
        const float* lAl = lA + lane;
        for (int s = wave; s < NT; s += 8) {
            const float vi = vcur[s];
            const float* rp = lAl + ((size_t)s << 9);
            #pragma unroll
            for (int k = 0; k < 8; ++k) {
                float sc = vi + rp[k << 6];
                if (sc > mv[k] || (sc == mv[k] && s < bi[k])) { mv[k] = sc; bi[k] = s; }
            }
        }
        #pragma unroll
        for (int k = 0; k < 8; ++k)
            part[wave][lane + (k << 6)] = make_float2(mv[k], __int_as_float(bi[k]));
        __syncthreads();
        float mval = NEG_INF; int bidx = 0x7fffffff;
        #pragma unroll
        for (int w = 0; w < 8; ++w) {
            const float2 q = part[w][j];
            const float val = q.x;
            const int   ii  = __float_as_int(q.y);
            if (val > mval || (val == mval && ii < bidx)) { mval = val; bidx = ii; }
        }
        __syncthreads();                     // vcur reads done
        float vn = mval + emis[(size_t)t * NT + j];
        bp[(size_t)t * NT + j] = (unsigned short)bidx;
        vcur[j] = vn;
        if (t == TT - 1) vlast[j] = vn;
        __syncthreads();
    }
}

// ---- backtrace: per-segment map composition (verified exact) ----
__launch_bounds__(NT, 1)
__global__ void bt_maps(const unsigned short* __restrict__ bp,
                        unsigned short* __restrict__ maps) {
    __shared__ unsigned short bps[BT_L * NT];
    const int s = blockIdx.x;
    const int tlo = BT_L * s + 1;
    int thi = BT_L * (s + 1); if (thi > TT - 1) thi = TT - 1;
    const int nt = thi - tlo + 1;
    for (int k = threadIdx.x; k < nt * NT; k += NT)
        bps[k] = bp[(size_t)tlo * NT + k];
    __syncthreads();
    int cur = threadIdx.x;
    for (int r = nt - 1; r >= 0; --r) cur = bps[r * NT + cur];
    maps[s * NT + threadIdx.x] = (unsigned short)cur;
}

__launch_bounds__(NT, 1)
__global__ void bt_bound(const float* __restrict__ vlast,
                         const unsigned short* __restrict__ maps,
                         int* __restrict__ bound) {
    __shared__ float sv[NT];
    __shared__ int   si[NT];
    int j = threadIdx.x;
    sv[j] = vlast[j]; si[j] = j;
    __syncthreads();
    for (int off = NT / 2; off > 0; off >>= 1) {
        if (j < off) {
            float v2 = sv[j + off]; int i2 = si[j + off];
            if (v2 > sv[j] || (v2 == sv[j] && i2 < si[j])) { sv[j] = v2; si[j] = i2; }
        }
        __syncthreads();
    }
    if (j == 0) {
        int cur = si[0];
        bound[BT_S] = cur;
        for (int s = BT_S - 1; s >= 0; --s) {
            cur = maps[s * NT + cur];
            bound[s] = cur;
        }
    }
}

__launch_bounds__(NT, 1)
__global__ void bt_path(const unsigned short* __restrict__ bp,
                        const int* __restrict__ bound,
                        int* __restrict__ path) {
    __shared__ unsigned short bps[BT_L * NT];
    const int s = blockIdx.x;
    const int tlo = BT_L * s + 1;
    int thi = BT_L * (s + 1); if (thi > TT - 1) thi = TT - 1;
    const int nt = thi - tlo + 1;
    for (int k = threadIdx.x; k < nt * NT; k += NT)
        bps[k] = bp[(size_t)tlo * NT + k];
    __syncthreads();
    if (threadIdx.x == 0) {
        int cur = bound[s + 1];
        if (s == BT_S - 1) path[TT - 1] = cur;
        for (int r = nt - 1; r >= 0; --r) {
            cur = bps[r * NT + cur];
            path[tlo - 1 + r] = cur;
        }
    }
}

extern "C" void kernel_launch(void* const* d_in, const int* in_sizes, int n_in,
                              void* d_out, int out_size, void* d_ws, size_t ws_size,
                              hipStream_t stream) {
    const int*   tok = (const int*)d_in[0];
    const float* A   = (const float*)d_in[1];
    const float* B   = (const float*)d_in[2];
    const float* Pi  = (const float*)d_in[3];
    int* path = (int*)d_out;
    char* ws = (char*)d_ws;
    if (ws_size < (size_t)WS_NEED) return;

    float* logPi          = (float*)(ws + WS_LOGPI);
    float* vlast          = (float*)(ws + WS_VLAST);
    int*   bound          = (int*)(ws + WS_BOUND);
    int*   poison         = (int*)(ws + WS_FLAG);
    float* rowmax         = (float*)(ws + WS_ROWMAX);
    unsigned short* maps  = (unsigned short*)(ws + WS_MAPS);
    float* lA             = (float*)(ws + WS_LA);
    float* emis           = (float*)(ws + WS_EMIS);
    unsigned short* bpp   = (unsigned short*)(ws + WS_BP);

    prep_logs  <<<(NT * NT + NT + 256) / 256, 256, 0, stream>>>(A, Pi, lA, logPi, poison);
    prep_emis  <<<(TT * NT) / 256,            256, 0, stream>>>(B, tok, emis);
    prep_rowmax<<<NT, 256, 0, stream>>>(lA, rowmax);
    viterbi_fwd_exact<<<1, NT, 0, stream>>>(lA, rowmax, emis, logPi, bpp, vlast,
                                            poison, emis /*diag scratch*/);
    viterbi_fallback<<<1, NT, 0, stream>>>(lA, emis, logPi, poison, bpp, vlast);
    bt_maps  <<<BT_S, NT, 0, stream>>>(bpp, maps);
    bt_bound <<<1,    NT, 0, stream>>>(vlast, maps, bound);
    bt_path  <<<BT_S, NT, 0, stream>>>(bpp, bound, path);
}

// Round 8
// 82279.877 us; speedup vs baseline: 2.0647x; 2.0647x over previous
//
#include <hip/hip_runtime.h>
#include <cstdint>
#include <cstddef>
#include <math.h>

// Exact Viterbi decode: N=512 states, T=8192, M=50257 tokens.
// Forward recurrence computed bit-exactly by ONE 512-thread workgroup
// (8 waves; thread j owns column j; v_j lives in a REGISTER only).
// Exactness-preserving pruning (R0-R6 structure, HW-verified):
//   SV  = union over waves of {i : v_i >= wavemax - DELTA_W}
//   T   = min_j (achieved column max over SV)
//   rows with fl(v_i + R) < T (R = global max row-max; IEEE add monotone)
//   cannot win or tie any column; extras {fl(v+R) >= T} \ SV are handled
//   EXACTLY inline (rare tail; R7 proved they do occur => no poison/fallback).
// All merges: (value strict >, tie -> smaller index) => exact first-index
// argmax, order-independent; dup-pad merges idempotent.
//
// R8 changes vs R5 (R7's poison/fallback removed — it fired every run and
// the 150ms fallback masked the fwd kernel):
//  (a) column-parallel scan (R0 layout, already coalesced: wave reads
//      lA[i*512 + 64w..64w+63] = 256B) with an EXPLICIT 8-wide double-
//      buffered pipeline: read 8 SV entries + issue 8 independent global
//      loads for group g+1 while merging group g. Kills the ~1.4k cy/row
//      serialization R6 measured (LDS-idx -> addr -> load chains).
//  (b) emis prefetched one step ahead (nt load latency hidden under step).
//  (c) diagnostics on clean path: WRITE_SIZE pages P = mean_n + 512*b,
//      b = min(7, cyc_step>>11). decode: P=(WRITE_KB-8193)/4.

#define NT 512
#define TT 8192
#define MT 50257
#define DELTA_W 0.15f
#define NEG_INF (-3.402823466e38f)

#define BT_L 32                  // backtrace segment length
#define BT_S (TT / BT_L)         // 256 segments

// ---- workspace layout (bytes) ----
#define WS_LOGPI   0u            // 512 f32
#define WS_VLAST   2048u         // 512 f32
#define WS_BOUND   4096u         // 257 i32
#define WS_ROWMAX  5632u         // 512 f32
#define WS_MAPS    8192u         // 256*512 u16 = 262144
#define WS_LA      270336u       // 512*512 f32 = 1048576 (row-major logA)
#define WS_EMIS    1318912u      // 8192*512 f32 = 16777216 (diag scratch after fwd)
#define WS_BP      18096128u     // 8192*512 u16 = 8388608
#define WS_NEED    26484736u

// Correctly-rounded fp32 logs via fp64 (verified: absmax 0 vs numpy ref).
__global__ void prep_logs(const float* __restrict__ A, const float* __restrict__ Pi,
                          float* __restrict__ lA, float* __restrict__ logPi) {
    int idx = blockIdx.x * blockDim.x + threadIdx.x;
    if (idx < NT * NT) {
        lA[idx] = (float)log((double)A[idx]);
    } else if (idx < NT * NT + NT) {
        int j = idx - NT * NT;
        logPi[j] = (float)log((double)Pi[j]);
    }
}

__global__ void prep_rowmax(const float* __restrict__ lA, float* __restrict__ rowmax) {
    __shared__ float s[4];
    int i = blockIdx.x;
    int t = threadIdx.x;                    // 256 threads
    float m = fmaxf(lA[i * NT + t], lA[i * NT + t + 256]);
    for (int k = 32; k >= 1; k >>= 1) m = fmaxf(m, __shfl_xor(m, k, 64));
    if ((t & 63) == 0) s[t >> 6] = m;
    __syncthreads();
    if (t == 0) {
        float r = fmaxf(fmaxf(s[0], s[1]), fmaxf(s[2], s[3]));
        rowmax[i] = r;
    }
}

__global__ void prep_emis(const float* __restrict__ B, const int* __restrict__ tok,
                          float* __restrict__ emis) {
    int idx = blockIdx.x * blockDim.x + threadIdx.x;   // t*512 + j
    if (idx >= TT * NT) return;
    int t = idx >> 9;
    int j = idx & (NT - 1);
    int tk = tok[t];
    float e;
    if (tk < 0) e = (float)log((double)(1.0f / 512.0f));
    else        e = (float)log((double)B[(size_t)j * MT + tk]);
    emis[idx] = e;
}

// 512 threads / 8 waves. 3 barriers per step (R0 structure).
__launch_bounds__(NT, 1)
__global__ void viterbi_fwd_exact(const float* __restrict__ lA,
                                  const float* __restrict__ rowmax,
                                  const float* emis,          // aliases diag scratch
                                  const float* __restrict__ logPi,
                                  unsigned short* __restrict__ bp,
                                  float* __restrict__ vlast,
                                  float* scratch) {
    __shared__ float2 SV[2][560];            // double-buffered survivors (v, idx bits)
    __shared__ float2 SVX[560];              // extras (rare)
    __shared__ alignas(16) float redR[8];    // rowmax partials
    __shared__ alignas(16) float redT[8];    // T partials
    __shared__ int nCtr[2];
    __shared__ int nCtrX;
    __shared__ int Pshare;

    const int tid  = threadIdx.x;
    const int j    = tid;                    // column AND row owned
    const int lane = tid & 63;
    const int wave = tid >> 6;               // 0..7
    const unsigned long long below = (1ull << lane) - 1ull;
    const float* __restrict__ lAj = lA + j;

    // ---- preamble: warm lA into L2; R; counters; v0; emis prefetch ----
    float acc = 0.0f;
    {
        const float4* lAf4 = (const float4*)lA;
        for (int k = tid; k < (NT * NT) / 4; k += NT) acc += lAf4[k].x;
    }
    float r = rowmax[j];
    #pragma unroll
    for (int d = 1; d <= 32; d <<= 1) r = fmaxf(r, __shfl_xor(r, d, 64));
    if (lane == 0) redR[wave] = r;
    if (tid == 0) { nCtr[0] = 0; nCtr[1] = 0; nCtrX = 0; }
    __syncthreads();
    float4 rr0 = *(const float4*)redR;
    float4 rr1 = *(const float4*)(redR + 4);
    const float R = fmaxf(fmaxf(fmaxf(rr0.x, rr0.y), fmaxf(rr0.z, rr0.w)),
                          fmaxf(fmaxf(rr1.x, rr1.y), fmaxf(rr1.z, rr1.w)));
    if (acc == 1.2345e30f && j == 511) SVX[0].x = acc;   // keep warm loads alive

    float v = logPi[j] + emis[j];            // exact v0 (single-rounded == ref)
    float e_next = __builtin_nontemporal_load(emis + (size_t)NT + j);   // emis[1]
    long long c0 = 0, nAcc = 0;
    if (tid == 0) c0 = clock64();

    for (int t = 1; t < TT; ++t) {
        const int p = t & 1;
        // ---- PH1: emis carry + prefetch(t+1); per-wave select; compact ----
        const float e = e_next;
        {
            const int tn = (t + 1 < TT) ? t + 1 : TT - 1;
            e_next = __builtin_nontemporal_load(emis + (size_t)tn * NT + j);
        }
        float wm = v;
        #pragma unroll
        for (int d = 1; d <= 32; d <<= 1) wm = fmaxf(wm, __shfl_xor(wm, d, 64));
        bool pred = (v >= wm - DELTA_W);     // per-wave max always selected
        unsigned long long mk = __ballot(pred);
        int base = 0;
        if (lane == 0) base = atomicAdd(&nCtr[p], __popcll(mk));
        base = __shfl(base, 0, 64);
        if (pred) SV[p][base + __popcll(mk & below)] = make_float2(v, __int_as_float(j));
        if (tid == 0) nCtr[p ^ 1] = 0;       // old n consumed at t-1 post-B1
        __syncthreads();                     // B1: survivors final

        const int n   = nCtr[p];             // >= 8 (block-uniform)
        const int nm1 = n - 1;
        nAcc += n;

        // ---- PH2a: column scan, 8-wide double-buffered pipeline ----
        float mval = NEG_INF;
        int   bidx = 0x7fffffff;
        {
            float va[8], aa[8]; int ia[8];
            float vb[8], ab[8]; int ib[8];
            #pragma unroll
            for (int k = 0; k < 8; ++k) {    // group A = survivors 0..7 (n>=8)
                float2 sv = SV[p][k];
                va[k] = sv.x; ia[k] = __float_as_int(sv.y);
                aa[k] = lAj[(size_t)(unsigned)ia[k] << 9];
            }
            int s0 = 0;
            while (true) {
                const int sB = s0 + 8;
                const bool moreB = (sB < n);
                if (moreB) {                 // issue group B loads
                    #pragma unroll
                    for (int k = 0; k < 8; ++k) {
                        int s = sB + k; if (s > nm1) s = nm1;   // dup-pad
                        float2 sv = SV[p][s];
                        vb[k] = sv.x; ib[k] = __float_as_int(sv.y);
                        ab[k] = lAj[(size_t)(unsigned)ib[k] << 9];
                    }
                }
                #pragma unroll
                for (int k = 0; k < 8; ++k) {   // merge group A
                    float sc = va[k] + aa[k];   // single-rounded add == ref
                    if (sc > mval || (sc == mval && ia[k] < bidx)) {
                        mval = sc; bidx = ia[k];
                    }
                }
                if (!moreB) break;
                const int sA = sB + 8;
                const bool moreA = (sA < n);
                if (moreA) {                 // issue next group A loads
                    #pragma unroll
                    for (int k = 0; k < 8; ++k) {
                        int s = sA + k; if (s > nm1) s = nm1;
                        float2 sv = SV[p][s];
                        va[k] = sv.x; ia[k] = __float_as_int(sv.y);
                        aa[k] = lAj[(size_t)(unsigned)ia[k] << 9];
                    }
                }
                #pragma unroll
                for (int k = 0; k < 8; ++k) {   // merge group B
                    float sc = vb[k] + ab[k];
                    if (sc > mval || (sc == mval && ib[k] < bidx)) {
                        mval = sc; bidx = ib[k];
                    }
                }
                if (!moreA) break;
                s0 = sA;
            }
        }
        // T partials from SV-only achieved maxima (pre-extras, per proof)
        float tmin = mval;
        #pragma unroll
        for (int d = 1; d <= 32; d <<= 1) tmin = fminf(tmin, __shfl_xor(tmin, d, 64));
        if (lane == 0) redT[wave] = tmin;
        if (tid == 0) nCtrX = 0;             // old nX consumed at t-1 post-B3
        __syncthreads();                     // B2: redT visible

        // ---- PH2b: T; extras compact (rare) ----
        float4 t0 = *(const float4*)redT;
        float4 t1 = *(const float4*)(redT + 4);
        float T = fminf(fminf(fminf(t0.x, t0.y), fminf(t0.z, t0.w)),
                        fminf(fminf(t1.x, t1.y), fminf(t1.z, t1.w)));
        bool px = (v + R >= T) && !pred;     // fl(v+R) monotone upper bound
        unsigned long long mkx = __ballot(px);
        if (mkx != 0ull) {                   // rare
            int bx = 0;
            if (lane == 0) bx = atomicAdd(&nCtrX, __popcll(mkx));
            bx = __shfl(bx, 0, 64);
            if (px) SVX[bx + __popcll(mkx & below)] = make_float2(v, __int_as_float(j));
        }
        __syncthreads();                     // B3: SVX/nCtrX visible

        // ---- PH2c: rare extras scan (serial gather); finalize ----
        const int nX = nCtrX;                // block-uniform
        if (nX > 0) {
            for (int s0x = 0; s0x < nX; s0x += 16) {
                float2 q[16];
                #pragma unroll
                for (int k = 0; k < 16; ++k) {
                    int s = s0x + k;
                    q[k] = SVX[s < nX ? s : nX - 1];    // dup-pad idempotent
                }
                float a[16];
                #pragma unroll
                for (int k = 0; k < 16; ++k)
                    a[k] = lAj[(size_t)__float_as_int(q[k].y) * NT];
                #pragma unroll
                for (int k = 0; k < 16; ++k) {
                    float sc = q[k].x + a[k];
                    int   is = __float_as_int(q[k].y);
                    if (sc > mval || (sc == mval && is < bidx)) { mval = sc; bidx = is; }
                }
            }
        }
        float vn = mval + e;                 // single-rounded == ref
        __builtin_nontemporal_store((unsigned short)bidx, bp + (size_t)t * NT + j);
        if (t == TT - 1) vlast[j] = vn;
        v = vn;
    }

    // ---- diagnostics: P = mean_n + 512*min(7, cyc_step>>11) pages ----
    if (tid == 0) {
        long long cyc = (clock64() - c0) / (long long)(TT - 1);
        int b = (int)(cyc >> 11); if (b > 7) b = 7; if (b < 0) b = 0;
        int mn = (int)(nAcc / (long long)(TT - 1)); if (mn > 511) mn = 511;
        Pshare = mn + (b << 9);
    }
    __syncthreads();
    const int P = Pshare;                    // <= 4095 pages (fits emis region)
    for (int pg = 0; pg < P; ++pg) {
        unsigned long long val = ((unsigned long long)pg << 32) | (unsigned)tid;
        __builtin_nontemporal_store(val,
            (unsigned long long*)((char*)scratch + (size_t)pg * 4096) + tid);
    }
}

// ---- backtrace: per-segment map composition (verified exact) ----
__launch_bounds__(NT, 1)
__global__ void bt_maps(const unsigned short* __restrict__ bp,
                        unsigned short* __restrict__ maps) {
    __shared__ unsigned short bps[BT_L * NT];
    const int s = blockIdx.x;
    const int tlo = BT_L * s + 1;
    int thi = BT_L * (s + 1); if (thi > TT - 1) thi = TT - 1;
    const int nt = thi - tlo + 1;
    for (int k = threadIdx.x; k < nt * NT; k += NT)
        bps[k] = bp[(size_t)tlo * NT + k];
    __syncthreads();
    int cur = threadIdx.x;
    for (int r = nt - 1; r >= 0; --r) cur = bps[r * NT + cur];
    maps[s * NT + threadIdx.x] = (unsigned short)cur;
}

__launch_bounds__(NT, 1)
__global__ void bt_bound(const float* __restrict__ vlast,
                         const unsigned short* __restrict__ maps,
                         int* __restrict__ bound) {
    __shared__ float sv[NT];
    __shared__ int   si[NT];
    int j = threadIdx.x;
    sv[j] = vlast[j]; si[j] = j;
    __syncthreads();
    for (int off = NT / 2; off > 0; off >>= 1) {
        if (j < off) {
            float v2 = sv[j + off]; int i2 = si[j + off];
            if (v2 > sv[j] || (v2 == sv[j] && i2 < si[j])) { sv[j] = v2; si[j] = i2; }
        }
        __syncthreads();
    }
    if (j == 0) {
        int cur = si[0];
        bound[BT_S] = cur;
        for (int s = BT_S - 1; s >= 0; --s) {
            cur = maps[s * NT + cur];
            bound[s] = cur;
        }
    }
}

__launch_bounds__(NT, 1)
__global__ void bt_path(const unsigned short* __restrict__ bp,
                        const int* __restrict__ bound,
                        int* __restrict__ path) {
    __shared__ unsigned short bps[BT_L * NT];
    const int s = blockIdx.x;
    const int tlo = BT_L * s + 1;
    int thi = BT_L * (s + 1); if (thi > TT - 1) thi = TT - 1;
    const int nt = thi - tlo + 1;
    for (int k = threadIdx.x; k < nt * NT; k += NT)
        bps[k] = bp[(size_t)tlo * NT + k];
    __syncthreads();
    if (threadIdx.x == 0) {
        int cur = bound[s + 1];
        if (s == BT_S - 1) path[TT - 1] = cur;
        for (int r = nt - 1; r >= 0; --r) {
            cur = bps[r * NT + cur];
            path[tlo - 1 + r] = cur;
        }
    }
}

extern "C" void kernel_launch(void* const* d_in, const int* in_sizes, int n_in,
                              void* d_out, int out_size, void* d_ws, size_t ws_size,
                              hipStream_t stream) {
    const int*   tok = (const int*)d_in[0];
    const float* A   = (const float*)d_in[1];
    const float* B   = (const float*)d_in[2];
    const float* Pi  = (const float*)d_in[3];
    int* path = (int*)d_out;
    char* ws = (char*)d_ws;
    if (ws_size < (size_t)WS_NEED) return;

    float* logPi          = (float*)(ws + WS_LOGPI);
    float* vlast          = (float*)(ws + WS_VLAST);
    int*   bound          = (int*)(ws + WS_BOUND);
    float* rowmax         = (float*)(ws + WS_ROWMAX);
    unsigned short* maps  = (unsigned short*)(ws + WS_MAPS);
    float* lA             = (float*)(ws + WS_LA);
    float* emis           = (float*)(ws + WS_EMIS);
    unsigned short* bpp   = (unsigned short*)(ws + WS_BP);

    prep_logs  <<<(NT * NT + NT + 255) / 256, 256, 0, stream>>>(A, Pi, lA, logPi);
    prep_emis  <<<(TT * NT) / 256,            256, 0, stream>>>(B, tok, emis);
    prep_rowmax<<<NT, 256, 0, stream>>>(lA, rowmax);
    viterbi_fwd_exact<<<1, NT, 0, stream>>>(lA, rowmax, emis, logPi, bpp, vlast,
                                            emis /*diag scratch*/);
    bt_maps  <<<BT_S, NT, 0, stream>>>(bpp, maps);
    bt_bound <<<1,    NT, 0, stream>>>(vlast, maps, bound);
    bt_path  <<<BT_S, NT, 0, stream>>>(bpp, bound, path);
}

// Round 9
// 57182.532 us; speedup vs baseline: 2.9709x; 1.4389x over previous
//
#include <hip/hip_runtime.h>
#include <cstdint>
#include <cstddef>
#include <math.h>

// Exact Viterbi decode: N=512 states, T=8192, M=50257 tokens.
// ONE 512-thread workgroup; thread j owns column j and row j; v_j in register.
// Exactness-preserving pruning:
//   SV  = union over waves of {i : v_i >= wavemax - DELTA_W}
//   T   = min_c (achieved column max over SV)
//   row i with fl(v_i + rowmax_i) < T cannot win/tie any column (IEEE add
//   monotone; strictly below an achieved value). extras {fl(v+rowmax) >= T}
//   \ SV handled EXACTLY inline (rare tail). All merges: strict >, tie ->
//   smaller index => exact first-index argmax, order-independent; dup-pad
//   merges idempotent.
//
// R9: row-parallel scan (wave w owns survivors w+8k; lane owns cols
// lane+64k; 8 coalesced 256B loads per row) with group-of-4 double-buffered
// pipeline (R7's measured-fast structure); R6's conflict-free partial
// exchange; extras INLINE (R7's poison/fallback removed — it fired every
// run); per-row rowmax bound (tighter than global R). 4 barriers/step.
// Diagnostics in WRITE_SIZE: P = min(255,cyc_step>>8)*16 + bitlen(xSteps).

#define NT 512
#define TT 8192
#define MT 50257
#define DELTA_W 0.15f
#define NEG_INF (-3.402823466e38f)

#define BT_L 32                  // backtrace segment length
#define BT_S (TT / BT_L)         // 256 segments

// ---- workspace layout (bytes) ----
#define WS_LOGPI   0u            // 512 f32
#define WS_VLAST   2048u         // 512 f32
#define WS_BOUND   4096u         // 257 i32
#define WS_ROWMAX  5632u         // 512 f32
#define WS_MAPS    8192u         // 256*512 u16 = 262144
#define WS_LA      270336u       // 512*512 f32 = 1048576 (row-major logA)
#define WS_EMIS    1318912u      // 8192*512 f32 = 16777216 (diag scratch after fwd)
#define WS_BP      18096128u     // 8192*512 u16 = 8388608
#define WS_NEED    26484736u

// Correctly-rounded fp32 logs via fp64 (verified: absmax 0 vs numpy ref).
__global__ void prep_logs(const float* __restrict__ A, const float* __restrict__ Pi,
                          float* __restrict__ lA, float* __restrict__ logPi) {
    int idx = blockIdx.x * blockDim.x + threadIdx.x;
    if (idx < NT * NT) {
        lA[idx] = (float)log((double)A[idx]);
    } else if (idx < NT * NT + NT) {
        int j = idx - NT * NT;
        logPi[j] = (float)log((double)Pi[j]);
    }
}

__global__ void prep_rowmax(const float* __restrict__ lA, float* __restrict__ rowmax) {
    __shared__ float s[4];
    int i = blockIdx.x;
    int t = threadIdx.x;                    // 256 threads
    float m = fmaxf(lA[i * NT + t], lA[i * NT + t + 256]);
    for (int k = 32; k >= 1; k >>= 1) m = fmaxf(m, __shfl_xor(m, k, 64));
    if ((t & 63) == 0) s[t >> 6] = m;
    __syncthreads();
    if (t == 0) {
        float r = fmaxf(fmaxf(s[0], s[1]), fmaxf(s[2], s[3]));
        rowmax[i] = r;
    }
}

__global__ void prep_emis(const float* __restrict__ B, const int* __restrict__ tok,
                          float* __restrict__ emis) {
    int idx = blockIdx.x * blockDim.x + threadIdx.x;   // t*512 + j
    if (idx >= TT * NT) return;
    int t = idx >> 9;
    int j = idx & (NT - 1);
    int tk = tok[t];
    float e;
    if (tk < 0) e = (float)log((double)(1.0f / 512.0f));
    else        e = (float)log((double)B[(size_t)j * MT + tk]);
    emis[idx] = e;
}

// 512 threads / 8 waves. 4 barriers per step (common path).
__launch_bounds__(NT, 1)
__global__ void viterbi_fwd_exact(const float* __restrict__ lA,
                                  const float* __restrict__ rowmax,
                                  const float* emis,          // aliases diag scratch
                                  const float* __restrict__ logPi,
                                  unsigned short* __restrict__ bp,
                                  float* __restrict__ vlast,
                                  float* scratch) {
    __shared__ float2 SV[2][560];            // double-buffered survivors (v, idx bits)
    __shared__ float2 SVX[560];              // extras (rare)
    __shared__ alignas(16) float redR[8];    // rowmax partials
    __shared__ alignas(16) float redT[8];    // T partials
    __shared__ int nCtr[2];
    __shared__ int nCtrX;
    __shared__ int Pshare;
    __shared__ float2 part[8][NT];           // per-wave column partials (32 KiB)

    const int tid  = threadIdx.x;
    const int j    = tid;                    // column AND row owned
    const int lane = tid & 63;
    const int wave = tid >> 6;               // 0..7
    const unsigned long long below = (1ull << lane) - 1ull;
    const float* __restrict__ lAj = lA + j;

    // ---- preamble: warm lA into L2; R per-row copy; counters; v0 ----
    float acc = 0.0f;
    {
        const float4* lAf4 = (const float4*)lA;
        for (int k = tid; k < (NT * NT) / 4; k += NT) acc += lAf4[k].x;
    }
    float r = rowmax[j];
    const float rmaxOwn = r;                 // per-row bound (tighter than global R)
    #pragma unroll
    for (int d = 1; d <= 32; d <<= 1) r = fmaxf(r, __shfl_xor(r, d, 64));
    if (lane == 0) redR[wave] = r;
    if (tid == 0) { nCtr[0] = 0; nCtr[1] = 0; nCtrX = 0; }
    __syncthreads();
    if (acc == 1.2345e30f && j == 511) SVX[0].x = acc;   // keep warm loads alive

    float v = logPi[j] + emis[j];            // exact v0 (single-rounded == ref)
    float e_next = __builtin_nontemporal_load(emis + (size_t)NT + j);   // emis[1]
    long long c0 = 0;
    int xSteps = 0;
    if (tid == 0) c0 = clock64();

    for (int t = 1; t < TT; ++t) {
        const int p = t & 1;
        // ---- PH1: emis carry + prefetch(t+1); per-wave select; compact ----
        const float e = e_next;
        {
            const int tn = (t + 1 < TT) ? t + 1 : TT - 1;
            e_next = __builtin_nontemporal_load(emis + (size_t)tn * NT + j);
        }
        float wm = v;
        #pragma unroll
        for (int d = 1; d <= 32; d <<= 1) wm = fmaxf(wm, __shfl_xor(wm, d, 64));
        bool pred = (v >= wm - DELTA_W);     // per-wave max always selected
        unsigned long long mk = __ballot(pred);
        int base = 0;
        if (lane == 0) base = atomicAdd(&nCtr[p], __popcll(mk));
        base = __shfl(base, 0, 64);
        if (pred) SV[p][base + __popcll(mk & below)] = make_float2(v, __int_as_float(j));
        __syncthreads();                     // B1: survivors final

        const int n   = nCtr[p];             // >= 8 (block-uniform)
        const int nm1 = n - 1;
        if (tid == 0) { nCtr[p ^ 1] = 0; nCtrX = 0; }   // consumed pre-B1 / pre-B3

        // ---- PH2a: row-parallel scan; wave w owns rows w+8s; group-of-4 dbuf ----
        // lane owns cols lane+64k; per row 8 coalesced 256B loads (rp[k<<6]).
        float mv[8]; int bi[8];
        #pragma unroll
        for (int k = 0; k < 8; ++k) { mv[k] = NEG_INF; bi[k] = 0x7fffffff; }
        {
            const float* lAl = lA + lane;
            float ga[4][8], va[4]; int ia[4];
            float gb[4][8], vb[4]; int ib[4];
            #pragma unroll
            for (int q = 0; q < 4; ++q) {    // group A = rows wave+{0,8,16,24}
                int s = wave + (q << 3); int gs = s < n ? s : nm1;   // dup-pad
                float2 sv = SV[p][gs]; va[q] = sv.x; ia[q] = __float_as_int(sv.y);
                const float* rp = lAl + ((size_t)(unsigned)ia[q] << 9);
                #pragma unroll
                for (int k = 0; k < 8; ++k) ga[q][k] = rp[k << 6];
            }
            int s0 = wave;
            while (true) {
                const int sB = s0 + 32;
                const bool moreB = (sB < n);
                if (moreB) {                 // issue group B loads
                    #pragma unroll
                    for (int q = 0; q < 4; ++q) {
                        int s = sB + (q << 3); int gs = s < n ? s : nm1;
                        float2 sv = SV[p][gs]; vb[q] = sv.x; ib[q] = __float_as_int(sv.y);
                        const float* rp = lAl + ((size_t)(unsigned)ib[q] << 9);
                        #pragma unroll
                        for (int k = 0; k < 8; ++k) gb[q][k] = rp[k << 6];
                    }
                }
                #pragma unroll
                for (int q = 0; q < 4; ++q)  // merge group A
                    #pragma unroll
                    for (int k = 0; k < 8; ++k) {
                        float sc = va[q] + ga[q][k];     // single-rounded add == ref
                        if (sc > mv[k] || (sc == mv[k] && ia[q] < bi[k])) {
                            mv[k] = sc; bi[k] = ia[q];
                        }
                    }
                if (!moreB) break;
                const int sA = sB + 32;
                const bool moreA = (sA < n);
                if (moreA) {                 // issue next group A loads
                    #pragma unroll
                    for (int q = 0; q < 4; ++q) {
                        int s = sA + (q << 3); int gs = s < n ? s : nm1;
                        float2 sv = SV[p][gs]; va[q] = sv.x; ia[q] = __float_as_int(sv.y);
                        const float* rp = lAl + ((size_t)(unsigned)ia[q] << 9);
                        #pragma unroll
                        for (int k = 0; k < 8; ++k) ga[q][k] = rp[k << 6];
                    }
                }
                #pragma unroll
                for (int q = 0; q < 4; ++q)  // merge group B
                    #pragma unroll
                    for (int k = 0; k < 8; ++k) {
                        float sc = vb[q] + gb[q][k];
                        if (sc > mv[k] || (sc == mv[k] && ib[q] < bi[k])) {
                            mv[k] = sc; bi[k] = ib[q];
                        }
                    }
                if (!moreA) break;
                s0 = sA;
            }
        }
        // write partials: col lane+64k -> part[wave][lane+(k<<6)] (R6: 0 conflicts)
        #pragma unroll
        for (int k = 0; k < 8; ++k)
            part[wave][lane + (k << 6)] = make_float2(mv[k], __int_as_float(bi[k]));
        __syncthreads();                     // B2: partials visible

        // ---- PH2b: merge 8 partials for column j; tmin; redT ----
        float mval = NEG_INF;
        int   bidx = 0x7fffffff;
        #pragma unroll
        for (int w = 0; w < 8; ++w) {
            const float2 q = part[w][j];
            const float val = q.x;
            const int   ii  = __float_as_int(q.y);
            if (val > mval || (val == mval && ii < bidx)) { mval = val; bidx = ii; }
        }
        float tmin = mval;
        #pragma unroll
        for (int d = 1; d <= 32; d <<= 1) tmin = fminf(tmin, __shfl_xor(tmin, d, 64));
        if (lane == 0) redT[wave] = tmin;
        __syncthreads();                     // B3: redT visible

        // ---- PH2c: T; extras compact (rare; per-row bound) ----
        float4 t0 = *(const float4*)redT;
        float4 t1 = *(const float4*)(redT + 4);
        float T = fminf(fminf(fminf(t0.x, t0.y), fminf(t0.z, t0.w)),
                        fminf(fminf(t1.x, t1.y), fminf(t1.z, t1.w)));
        bool px = (v + rmaxOwn >= T) && !pred;   // fl(v+rmax_j) monotone bound
        unsigned long long mkx = __ballot(px);
        if (mkx != 0ull) {                   // rare
            int bx = 0;
            if (lane == 0) bx = atomicAdd(&nCtrX, __popcll(mkx));
            bx = __shfl(bx, 0, 64);
            if (px) SVX[bx + __popcll(mkx & below)] = make_float2(v, __int_as_float(j));
        }
        __syncthreads();                     // B4: SVX/nCtrX visible

        // ---- PH2d: rare extras scan (serial gather); finalize ----
        const int nX = nCtrX;                // block-uniform
        if (nX > 0) {
            ++xSteps;
            for (int s0x = 0; s0x < nX; s0x += 16) {
                float2 q[16];
                #pragma unroll
                for (int k = 0; k < 16; ++k) {
                    int s = s0x + k;
                    q[k] = SVX[s < nX ? s : nX - 1];    // dup-pad idempotent
                }
                float a[16];
                #pragma unroll
                for (int k = 0; k < 16; ++k)
                    a[k] = lAj[(size_t)__float_as_int(q[k].y) * NT];
                #pragma unroll
                for (int k = 0; k < 16; ++k) {
                    float sc = q[k].x + a[k];
                    int   is = __float_as_int(q[k].y);
                    if (sc > mval || (sc == mval && is < bidx)) { mval = sc; bidx = is; }
                }
            }
        }
        float vn = mval + e;                 // single-rounded == ref
        __builtin_nontemporal_store((unsigned short)bidx, bp + (size_t)t * NT + j);
        if (t == TT - 1) vlast[j] = vn;
        v = vn;
    }

    // ---- diagnostics: P = min(255,cyc>>8)*16 + bitlen(xSteps) ----
    if (tid == 0) {
        long long cyc = (clock64() - c0) / (long long)(TT - 1);
        int cb = (int)(cyc >> 8); if (cb > 255) cb = 255; if (cb < 0) cb = 0;
        int xb = 0; { unsigned x = (unsigned)xSteps; while (x) { ++xb; x >>= 1; } }
        if (xb > 15) xb = 15;
        Pshare = cb * 16 + xb;
    }
    __syncthreads();
    const int P = Pshare;                    // <= 4095 pages (fits emis region)
    for (int pg = 0; pg < P; ++pg) {
        unsigned long long val = ((unsigned long long)pg << 32) | (unsigned)tid;
        __builtin_nontemporal_store(val,
            (unsigned long long*)((char*)scratch + (size_t)pg * 4096) + tid);
    }
}

// ---- backtrace: per-segment map composition (verified exact) ----
__launch_bounds__(NT, 1)
__global__ void bt_maps(const unsigned short* __restrict__ bp,
                        unsigned short* __restrict__ maps) {
    __shared__ unsigned short bps[BT_L * NT];
    const int s = blockIdx.x;
    const int tlo = BT_L * s + 1;
    int thi = BT_L * (s + 1); if (thi > TT - 1) thi = TT - 1;
    const int nt = thi - tlo + 1;
    for (int k = threadIdx.x; k < nt * NT; k += NT)
        bps[k] = bp[(size_t)tlo * NT + k];
    __syncthreads();
    int cur = threadIdx.x;
    for (int r = nt - 1; r >= 0; --r) cur = bps[r * NT + cur];
    maps[s * NT + threadIdx.x] = (unsigned short)cur;
}

__launch_bounds__(NT, 1)
__global__ void bt_bound(const float* __restrict__ vlast,
                         const unsigned short* __restrict__ maps,
                         int* __restrict__ bound) {
    __shared__ float sv[NT];
    __shared__ int   si[NT];
    int j = threadIdx.x;
    sv[j] = vlast[j]; si[j] = j;
    __syncthreads();
    for (int off = NT / 2; off > 0; off >>= 1) {
        if (j < off) {
            float v2 = sv[j + off]; int i2 = si[j + off];
            if (v2 > sv[j] || (v2 == sv[j] && i2 < si[j])) { sv[j] = v2; si[j] = i2; }
        }
        __syncthreads();
    }
    if (j == 0) {
        int cur = si[0];
        bound[BT_S] = cur;
        for (int s = BT_S - 1; s >= 0; --s) {
            cur = maps[s * NT + cur];
            bound[s] = cur;
        }
    }
}

__launch_bounds__(NT, 1)
__global__ void bt_path(const unsigned short* __restrict__ bp,
                        const int* __restrict__ bound,
                        int* __restrict__ path) {
    __shared__ unsigned short bps[BT_L * NT];
    const int s = blockIdx.x;
    const int tlo = BT_L * s + 1;
    int thi = BT_L * (s + 1); if (thi > TT - 1) thi = TT - 1;
    const int nt = thi - tlo + 1;
    for (int k = threadIdx.x; k < nt * NT; k += NT)
        bps[k] = bp[(size_t)tlo * NT + k];
    __syncthreads();
    if (threadIdx.x == 0) {
        int cur = bound[s + 1];
        if (s == BT_S - 1) path[TT - 1] = cur;
        for (int r = nt - 1; r >= 0; --r) {
            cur = bps[r * NT + cur];
            path[tlo - 1 + r] = cur;
        }
    }
}

extern "C" void kernel_launch(void* const* d_in, const int* in_sizes, int n_in,
                              void* d_out, int out_size, void* d_ws, size_t ws_size,
                              hipStream_t stream) {
    const int*   tok = (const int*)d_in[0];
    const float* A   = (const float*)d_in[1];
    const float* B   = (const float*)d_in[2];
    const float* Pi  = (const float*)d_in[3];
    int* path = (int*)d_out;
    char* ws = (char*)d_ws;
    if (ws_size < (size_t)WS_NEED) return;

    float* logPi          = (float*)(ws + WS_LOGPI);
    float* vlast          = (float*)(ws + WS_VLAST);
    int*   bound          = (int*)(ws + WS_BOUND);
    float* rowmax         = (float*)(ws + WS_ROWMAX);
    unsigned short* maps  = (unsigned short*)(ws + WS_MAPS);
    float* lA             = (float*)(ws + WS_LA);
    float* emis           = (float*)(ws + WS_EMIS);
    unsigned short* bpp   = (unsigned short*)(ws + WS_BP);

    prep_logs  <<<(NT * NT + NT + 255) / 256, 256, 0, stream>>>(A, Pi, lA, logPi);
    prep_emis  <<<(TT * NT) / 256,            256, 0, stream>>>(B, tok, emis);
    prep_rowmax<<<NT, 256, 0, stream>>>(lA, rowmax);
    viterbi_fwd_exact<<<1, NT, 0, stream>>>(lA, rowmax, emis, logPi, bpp, vlast,
                                            emis /*diag scratch*/);
    bt_maps  <<<BT_S, NT, 0, stream>>>(bpp, maps);
    bt_bound <<<1,    NT, 0, stream>>>(vlast, maps, bound);
    bt_path  <<<BT_S, NT, 0, stream>>>(bpp, bound, path);
}